// Round 1
// baseline (1188.921 us; speedup 1.0000x reference)
//
#include <hip/hip_runtime.h>
#include <hip/hip_bf16.h>

#define B_ 4
#define H_ 16
#define L_ 2048
#define D_ 128
#define BH_ 64

typedef __attribute__((ext_vector_type(8))) _Float16 f16x8;
typedef __attribute__((ext_vector_type(4))) float f32x4;

// ---------------------------------------------------------------------------
// Kernel 1: q/k projections (f16 MFMA, f32 accum, +bias) and x -> V^T (f16).
//   Qb, Kb: [BH, L, D] f16 row-major
//   VT:     [BH, D, L] f16 row-major (transposed x)
// Block: 256 threads = 4 waves, each wave does 16 rows of the 64-row tile.
// ---------------------------------------------------------------------------
__global__ __launch_bounds__(256) void proj_tr_kernel(
    const float* __restrict__ x,
    const float* __restrict__ W1, const float* __restrict__ b1,
    const float* __restrict__ W2, const float* __restrict__ b2,
    _Float16* __restrict__ Qb, _Float16* __restrict__ Kb,
    _Float16* __restrict__ VT)
{
  const int tid  = threadIdx.x;
  const int wave = tid >> 6;
  const int lane = tid & 63;
  const int lhi  = lane >> 4;   // 0..3
  const int llo  = lane & 15;   // 0..15
  const int r0   = blockIdx.x * 64;    // global row base (rows = bh*L + l)
  const int wr0  = r0 + wave * 16;

  // ---- A fragments: A[i][k], i = llo (row), k = lhi*8+e (+ks*32) ----
  f16x8 a[4];
#pragma unroll
  for (int ks = 0; ks < 4; ++ks) {
    const float* p = x + (size_t)(wr0 + llo) * D_ + lhi * 8 + ks * 32;
    f16x8 t;
#pragma unroll
    for (int e = 0; e < 8; ++e) t[e] = (_Float16)p[e];
    a[ks] = t;
  }

  f32x4 accq[8], acck[8];
#pragma unroll
  for (int n = 0; n < 8; ++n) {
    accq[n] = (f32x4){0.f, 0.f, 0.f, 0.f};
    acck[n] = (f32x4){0.f, 0.f, 0.f, 0.f};
  }

#pragma unroll
  for (int n = 0; n < 8; ++n) {
    const int e = n * 16 + llo;       // output feature (B-frag col)
#pragma unroll
    for (int ks = 0; ks < 4; ++ks) {
      const float* p1 = W1 + e * D_ + lhi * 8 + ks * 32;
      const float* p2 = W2 + e * D_ + lhi * 8 + ks * 32;
      f16x8 w1f, w2f;
#pragma unroll
      for (int q = 0; q < 8; ++q) {
        w1f[q] = (_Float16)p1[q];
        w2f[q] = (_Float16)p2[q];
      }
      accq[n] = __builtin_amdgcn_mfma_f32_16x16x32_f16(a[ks], w1f, accq[n], 0, 0, 0);
      acck[n] = __builtin_amdgcn_mfma_f32_16x16x32_f16(a[ks], w2f, acck[n], 0, 0, 0);
    }
  }

  // ---- store q,k (C/D layout: row = lhi*4+r, col = n*16+llo) ----
#pragma unroll
  for (int n = 0; n < 8; ++n) {
    const int e = n * 16 + llo;
    const float bias1 = b1[e];
    const float bias2 = b2[e];
#pragma unroll
    for (int r = 0; r < 4; ++r) {
      const size_t row = (size_t)wr0 + lhi * 4 + r;
      Qb[row * D_ + e] = (_Float16)(accq[n][r] + bias1);
      Kb[row * D_ + e] = (_Float16)(acck[n][r] + bias2);
    }
  }

  // ---- transpose: VT[bh][d][l] = x[bh][l][d] (coalesced reads & writes) ----
  const int bh = r0 / L_;
  const int l0 = r0 % L_;
  const int d  = tid & 127;
  const int rh = tid >> 7;  // 0 or 1 (rows 0..31 / 32..63 of tile)
  _Float16* dst = VT + (size_t)bh * D_ * L_ + (size_t)d * L_ + l0 + rh * 32;
#pragma unroll
  for (int j = 0; j < 4; ++j) {
    f16x8 t;
#pragma unroll
    for (int e = 0; e < 8; ++e)
      t[e] = (_Float16)x[(size_t)(r0 + rh * 32 + j * 8 + e) * D_ + d];
    *(f16x8*)(dst + j * 8) = t;
  }
}

// ---------------------------------------------------------------------------
// Kernel 2: fused gelu(QK^T) -> softmax -> @V flash attention.
// Grid: BH * (L/64) blocks; 4 waves, each owns 16 q-rows. KV tile = 64.
// ---------------------------------------------------------------------------
__global__ __launch_bounds__(256) void attn_kernel(
    const _Float16* __restrict__ Qb, const _Float16* __restrict__ Kb,
    const _Float16* __restrict__ VT, float* __restrict__ out)
{
  __shared__ _Float16 plds[4][1024];  // per-wave 16x64 P tile (swizzled)

  const int tid  = threadIdx.x;
  const int wave = tid >> 6;
  const int lane = tid & 63;
  const int lhi  = lane >> 4;
  const int llo  = lane & 15;
  const int blk  = blockIdx.x;
  const int bh   = blk >> 5;          // 32 q-tiles per head
  const int q0   = (blk & 31) * 64;
  const int b    = bh >> 4;
  const int h    = bh & 15;
  const int wq0  = q0 + wave * 16;

  const _Float16* Kbase = Kb + (size_t)bh * L_ * D_;
  const _Float16* Vbase = VT + (size_t)bh * D_ * L_;

  // Q fragments (A): i = llo, k = lhi*8+e + ks*32
  f16x8 qf[4];
#pragma unroll
  for (int ks = 0; ks < 4; ++ks)
    qf[ks] = *(const f16x8*)(Qb + ((size_t)bh * L_ + wq0 + llo) * D_ + lhi * 8 + ks * 32);

  f32x4 accO[8];
#pragma unroll
  for (int n = 0; n < 8; ++n) accO[n] = (f32x4){0.f, 0.f, 0.f, 0.f};
  float mreg[4] = {-1e30f, -1e30f, -1e30f, -1e30f};
  float lreg[4] = {0.f, 0.f, 0.f, 0.f};

  _Float16* pw = plds[wave];

  for (int j0 = 0; j0 < L_; j0 += 64) {
    // ---- S = Q K^T (16 x 64) ----
    f32x4 s[4];
#pragma unroll
    for (int js = 0; js < 4; ++js) s[js] = (f32x4){0.f, 0.f, 0.f, 0.f};
#pragma unroll
    for (int js = 0; js < 4; ++js) {
      const _Float16* krow = Kbase + (size_t)(j0 + js * 16 + llo) * D_ + lhi * 8;
#pragma unroll
      for (int ks = 0; ks < 4; ++ks) {
        f16x8 kf = *(const f16x8*)(krow + ks * 32);
        s[js] = __builtin_amdgcn_mfma_f32_16x16x32_f16(qf[ks], kf, s[js], 0, 0, 0);
      }
    }
    // ---- exact-erf GELU on raw scores ----
#pragma unroll
    for (int js = 0; js < 4; ++js)
#pragma unroll
      for (int r = 0; r < 4; ++r) {
        float v = s[js][r];
        s[js][r] = 0.5f * v * (1.f + erff(v * 0.70710678118f));
      }
    // ---- online softmax (row r of this lane group = lhi*4+r) ----
#pragma unroll
    for (int r = 0; r < 4; ++r) {
      float tm = fmaxf(fmaxf(s[0][r], s[1][r]), fmaxf(s[2][r], s[3][r]));
      tm = fmaxf(tm, __shfl_xor(tm, 1));
      tm = fmaxf(tm, __shfl_xor(tm, 2));
      tm = fmaxf(tm, __shfl_xor(tm, 4));
      tm = fmaxf(tm, __shfl_xor(tm, 8));
      float mn = fmaxf(mreg[r], tm);
      float sc = __expf(mreg[r] - mn);
      mreg[r] = mn;
      float ts = 0.f;
#pragma unroll
      for (int js = 0; js < 4; ++js) {
        float p = __expf(s[js][r] - mn);
        s[js][r] = p;
        ts += p;
      }
      ts += __shfl_xor(ts, 1);
      ts += __shfl_xor(ts, 2);
      ts += __shfl_xor(ts, 4);
      ts += __shfl_xor(ts, 8);
      lreg[r] = lreg[r] * sc + ts;
#pragma unroll
      for (int n = 0; n < 8; ++n) accO[n][r] *= sc;
    }
    // ---- P -> LDS (xor-swizzled to kill row-major bank conflicts) ----
#pragma unroll
    for (int js = 0; js < 4; ++js)
#pragma unroll
      for (int r = 0; r < 4; ++r) {
        const int row = lhi * 4 + r;
        const int idx = (row * 64 + js * 16 + llo) ^ ((row & 7) << 3);
        pw[idx] = (_Float16)s[js][r];
      }
    __syncthreads();
    // ---- O += P @ V ----
#pragma unroll
    for (int ks2 = 0; ks2 < 2; ++ks2) {
      const int koff = lhi * 8 + ks2 * 32;
      const int ridx = (llo * 64 + koff) ^ ((llo & 7) << 3);
      f16x8 pf = *(const f16x8*)(pw + ridx);
#pragma unroll
      for (int n = 0; n < 8; ++n) {
        const _Float16* vrow = Vbase + (size_t)(n * 16 + llo) * L_ + j0 + koff;
        f16x8 vf = *(const f16x8*)vrow;
        accO[n] = __builtin_amdgcn_mfma_f32_16x16x32_f16(pf, vf, accO[n], 0, 0, 0);
      }
    }
    __syncthreads();
  }

  // ---- epilogue: divide by l, write out[b][i][h*D+d] (f32) ----
#pragma unroll
  for (int r = 0; r < 4; ++r) lreg[r] = 1.f / lreg[r];
#pragma unroll
  for (int n = 0; n < 8; ++n) {
    const int dcol = n * 16 + llo;
#pragma unroll
    for (int r = 0; r < 4; ++r) {
      const int i = wq0 + lhi * 4 + r;
      out[((size_t)(b * L_ + i) * H_ + h) * D_ + dcol] = accO[n][r] * lreg[r];
    }
  }
}

extern "C" void kernel_launch(void* const* d_in, const int* in_sizes, int n_in,
                              void* d_out, int out_size, void* d_ws, size_t ws_size,
                              hipStream_t stream) {
  const float* x  = (const float*)d_in[0];
  const float* W1 = (const float*)d_in[1];
  const float* b1 = (const float*)d_in[2];
  const float* W2 = (const float*)d_in[3];
  const float* b2 = (const float*)d_in[4];
  float* out = (float*)d_out;

  const size_t N = (size_t)BH_ * L_ * D_;   // 16,777,216 elements
  _Float16* Qb = (_Float16*)d_ws;
  _Float16* Kb = Qb + N;
  _Float16* VT = Kb + N;   // total f16 workspace: 3*N*2 B = ~100.7 MB

  proj_tr_kernel<<<(BH_ * L_) / 64, 256, 0, stream>>>(x, W1, b1, W2, b2, Qb, Kb, VT);
  attn_kernel<<<BH_ * (L_ / 64), 256, 0, stream>>>(Qb, Kb, VT, out);
}

// Round 2
// 1182.323 us; speedup vs baseline: 1.0056x; 1.0056x over previous
//
#include <hip/hip_runtime.h>
#include <hip/hip_bf16.h>

#define B_ 4
#define H_ 16
#define L_ 2048
#define D_ 128
#define BH_ 64

typedef __attribute__((ext_vector_type(8))) _Float16 f16x8;
typedef __attribute__((ext_vector_type(4))) _Float16 f16x4;
typedef __attribute__((ext_vector_type(4))) float f32x4;

#define L2E 1.44269504088896f

// Exact-erf GELU via Abramowitz-Stegun 7.1.26 (|erf err| < 1.5e-7), branch-free:
// ~14 VALU ops (1 v_rcp + 1 v_exp + FMAs) vs libm erff's divergent ~60+.
__device__ __forceinline__ float gelu_exact(float v) {
  float x  = v * 0.70710678118f;
  float ax = __builtin_fabsf(x);
  float t  = __builtin_amdgcn_rcpf(__builtin_fmaf(0.3275911f, ax, 1.0f));
  float poly = t * __builtin_fmaf(t,
                 __builtin_fmaf(t,
                   __builtin_fmaf(t,
                     __builtin_fmaf(t, 1.061405429f, -1.453152027f),
                   1.421413741f),
                 -0.284496736f),
               0.254829592f);
  float e    = __builtin_amdgcn_exp2f(-L2E * x * x);
  float erfa = __builtin_fmaf(-poly, e, 1.0f);
  float erfx = copysignf(erfa, x);
  return 0.5f * v * (1.0f + erfx);
}

// ---------------------------------------------------------------------------
// Kernel 1: q/k projections (f16 MFMA, f32 accum, +bias) and x -> V^T (f16).
//   Qb, Kb: [BH, L, D] f16 row-major;  VT: [BH, D, L] f16 row-major
// ---------------------------------------------------------------------------
__global__ __launch_bounds__(256) void proj_tr_kernel(
    const float* __restrict__ x,
    const float* __restrict__ W1, const float* __restrict__ b1,
    const float* __restrict__ W2, const float* __restrict__ b2,
    _Float16* __restrict__ Qb, _Float16* __restrict__ Kb,
    _Float16* __restrict__ VT)
{
  const int tid  = threadIdx.x;
  const int wave = tid >> 6;
  const int lane = tid & 63;
  const int lhi  = lane >> 4;
  const int llo  = lane & 15;
  const int r0   = blockIdx.x * 64;
  const int wr0  = r0 + wave * 16;

  f16x8 a[4];
#pragma unroll
  for (int ks = 0; ks < 4; ++ks) {
    const float* p = x + (size_t)(wr0 + llo) * D_ + lhi * 8 + ks * 32;
    f16x8 t;
#pragma unroll
    for (int e = 0; e < 8; ++e) t[e] = (_Float16)p[e];
    a[ks] = t;
  }

  f32x4 accq[8], acck[8];
#pragma unroll
  for (int n = 0; n < 8; ++n) {
    accq[n] = (f32x4){0.f, 0.f, 0.f, 0.f};
    acck[n] = (f32x4){0.f, 0.f, 0.f, 0.f};
  }

#pragma unroll
  for (int n = 0; n < 8; ++n) {
    const int e = n * 16 + llo;
#pragma unroll
    for (int ks = 0; ks < 4; ++ks) {
      const float* p1 = W1 + e * D_ + lhi * 8 + ks * 32;
      const float* p2 = W2 + e * D_ + lhi * 8 + ks * 32;
      f16x8 w1f, w2f;
#pragma unroll
      for (int q = 0; q < 8; ++q) {
        w1f[q] = (_Float16)p1[q];
        w2f[q] = (_Float16)p2[q];
      }
      accq[n] = __builtin_amdgcn_mfma_f32_16x16x32_f16(a[ks], w1f, accq[n], 0, 0, 0);
      acck[n] = __builtin_amdgcn_mfma_f32_16x16x32_f16(a[ks], w2f, acck[n], 0, 0, 0);
    }
  }

#pragma unroll
  for (int n = 0; n < 8; ++n) {
    const int e = n * 16 + llo;
    const float bias1 = b1[e];
    const float bias2 = b2[e];
#pragma unroll
    for (int r = 0; r < 4; ++r) {
      const size_t row = (size_t)wr0 + lhi * 4 + r;
      Qb[row * D_ + e] = (_Float16)(accq[n][r] + bias1);
      Kb[row * D_ + e] = (_Float16)(acck[n][r] + bias2);
    }
  }

  const int bh = r0 / L_;
  const int l0 = r0 % L_;
  const int d  = tid & 127;
  const int rh = tid >> 7;
  _Float16* dst = VT + (size_t)bh * D_ * L_ + (size_t)d * L_ + l0 + rh * 32;
#pragma unroll
  for (int j = 0; j < 4; ++j) {
    f16x8 t;
#pragma unroll
    for (int e = 0; e < 8; ++e)
      t[e] = (_Float16)x[(size_t)(r0 + rh * 32 + j * 8 + e) * D_ + d];
    *(f16x8*)(dst + j * 8) = t;
  }
}

// ---------------------------------------------------------------------------
// Kernel 2: fused gelu(QK^T) -> softmax -> @V flash attention.
// Swapped QK^T: S^T = mfma(K, Q) puts a full q-row's scores in one lane
// (q = llo, k = j0 + js*16 + lhi*4 + r) -> in-lane softmax reduce + 2 shfls.
// Wave-private LDS P buffer, NO barriers (waves fully independent).
// ---------------------------------------------------------------------------
__global__ __launch_bounds__(256) void attn_kernel(
    const _Float16* __restrict__ Qb, const _Float16* __restrict__ Kb,
    const _Float16* __restrict__ VT, float* __restrict__ out)
{
  __shared__ _Float16 plds[4][1024];

  const int tid  = threadIdx.x;
  const int wave = tid >> 6;
  const int lane = tid & 63;
  const int lhi  = lane >> 4;
  const int llo  = lane & 15;
  const int blk  = blockIdx.x;
  const int bh   = blk >> 5;
  const int q0   = (blk & 31) * 64;
  const int b    = bh >> 4;
  const int h    = bh & 15;
  const int wq0  = q0 + wave * 16;

  const _Float16* Kbase = Kb + (size_t)bh * L_ * D_;
  const _Float16* Vbase = VT + (size_t)bh * D_ * L_;

  // Q fragments (B-operand of swapped QK^T): col j = llo = q-row, k = lhi*8+e
  f16x8 qf[4];
#pragma unroll
  for (int ks = 0; ks < 4; ++ks)
    qf[ks] = *(const f16x8*)(Qb + ((size_t)bh * L_ + wq0 + llo) * D_ + lhi * 8 + ks * 32);

  f32x4 accO[8];
#pragma unroll
  for (int n = 0; n < 8; ++n) accO[n] = (f32x4){0.f, 0.f, 0.f, 0.f};
  float m = -1e30f;
  float l = 0.f;

  _Float16* pw = plds[wave];
  const int swz = (llo & 7) << 3;
  const int wb  = llo * 64 + lhi * 4;   // P-write base (half index, pre-swizzle)

  for (int j0 = 0; j0 < L_; j0 += 64) {
    // ---- S^T = K Q^T : lane holds S[q=llo][k=j0+js*16+lhi*4+r] ----
    f32x4 s[4];
#pragma unroll
    for (int js = 0; js < 4; ++js) s[js] = (f32x4){0.f, 0.f, 0.f, 0.f};
#pragma unroll
    for (int js = 0; js < 4; ++js) {
      const _Float16* krow = Kbase + (size_t)(j0 + js * 16 + llo) * D_ + lhi * 8;
#pragma unroll
      for (int ks = 0; ks < 4; ++ks) {
        f16x8 kf = *(const f16x8*)(krow + ks * 32);
        s[js] = __builtin_amdgcn_mfma_f32_16x16x32_f16(kf, qf[ks], s[js], 0, 0, 0);
      }
    }
    // ---- exact-erf GELU (fast branch-free) ----
    float g[4][4];
#pragma unroll
    for (int js = 0; js < 4; ++js)
#pragma unroll
      for (int r = 0; r < 4; ++r) g[js][r] = gelu_exact(s[js][r]);

    // ---- online softmax: row is lane-local; full row across lhi groups ----
    float tm = fmaxf(fmaxf(fmaxf(g[0][0], g[0][1]), fmaxf(g[0][2], g[0][3])),
                     fmaxf(fmaxf(g[1][0], g[1][1]), fmaxf(g[1][2], g[1][3])));
    float tm2 = fmaxf(fmaxf(fmaxf(g[2][0], g[2][1]), fmaxf(g[2][2], g[2][3])),
                      fmaxf(fmaxf(g[3][0], g[3][1]), fmaxf(g[3][2], g[3][3])));
    tm = fmaxf(tm, tm2);
    tm = fmaxf(tm, __shfl_xor(tm, 16));
    tm = fmaxf(tm, __shfl_xor(tm, 32));

    float mn  = fmaxf(m, tm);
    float mnl = mn * L2E;
    float sc  = __builtin_amdgcn_exp2f(__builtin_fmaf(m, L2E, -mnl));
    m = mn;

    float ts = 0.f;
    f16x4 pj[4];
#pragma unroll
    for (int js = 0; js < 4; ++js) {
#pragma unroll
      for (int r = 0; r < 4; ++r) {
        float p = __builtin_amdgcn_exp2f(__builtin_fmaf(g[js][r], L2E, -mnl));
        ts += p;
        pj[js][r] = (_Float16)p;
      }
    }
    ts += __shfl_xor(ts, 16);
    ts += __shfl_xor(ts, 32);
    l = __builtin_fmaf(l, sc, ts);

    // ---- rescale accO (rows live at lhi*4+r; sc lives in lane llo=row) ----
    float scb[4];
#pragma unroll
    for (int r = 0; r < 4; ++r) scb[r] = __shfl(sc, lhi * 4 + r);
#pragma unroll
    for (int n = 0; n < 8; ++n)
#pragma unroll
      for (int r = 0; r < 4; ++r) accO[n][r] *= scb[r];

    // ---- P -> wave-private LDS (4x ds_write_b64, xor-swizzled) ----
#pragma unroll
    for (int js = 0; js < 4; ++js)
      *(f16x4*)(pw + ((wb + js * 16) ^ swz)) = pj[js];

    // ---- O += P @ V ----
#pragma unroll
    for (int ks2 = 0; ks2 < 2; ++ks2) {
      const int koff = lhi * 8 + ks2 * 32;
      f16x8 pf = *(const f16x8*)(pw + ((llo * 64 + koff) ^ swz));
#pragma unroll
      for (int n = 0; n < 8; ++n) {
        const _Float16* vrow = Vbase + (size_t)(n * 16 + llo) * L_ + j0 + koff;
        f16x8 vf = *(const f16x8*)vrow;
        accO[n] = __builtin_amdgcn_mfma_f32_16x16x32_f16(pf, vf, accO[n], 0, 0, 0);
      }
    }
  }

  // ---- epilogue ----
  float linv = __builtin_amdgcn_rcpf(l);
  float lb[4];
#pragma unroll
  for (int r = 0; r < 4; ++r) lb[r] = __shfl(linv, lhi * 4 + r);
#pragma unroll
  for (int n = 0; n < 8; ++n) {
    const int dcol = n * 16 + llo;
#pragma unroll
    for (int r = 0; r < 4; ++r) {
      const int i = wq0 + lhi * 4 + r;
      out[((size_t)(b * L_ + i) * H_ + h) * D_ + dcol] = accO[n][r] * lb[r];
    }
  }
}

extern "C" void kernel_launch(void* const* d_in, const int* in_sizes, int n_in,
                              void* d_out, int out_size, void* d_ws, size_t ws_size,
                              hipStream_t stream) {
  const float* x  = (const float*)d_in[0];
  const float* W1 = (const float*)d_in[1];
  const float* b1 = (const float*)d_in[2];
  const float* W2 = (const float*)d_in[3];
  const float* b2 = (const float*)d_in[4];
  float* out = (float*)d_out;

  const size_t N = (size_t)BH_ * L_ * D_;
  _Float16* Qb = (_Float16*)d_ws;
  _Float16* Kb = Qb + N;
  _Float16* VT = Kb + N;

  proj_tr_kernel<<<(BH_ * L_) / 64, 256, 0, stream>>>(x, W1, b1, W2, b2, Qb, Kb, VT);
  attn_kernel<<<BH_ * (L_ / 64), 256, 0, stream>>>(Qb, Kb, VT, out);
}

// Round 3
// 471.591 us; speedup vs baseline: 2.5211x; 2.5071x over previous
//
#include <hip/hip_runtime.h>
#include <hip/hip_bf16.h>

#define B_ 4
#define H_ 16
#define L_ 2048
#define D_ 128
#define BH_ 64

typedef __attribute__((ext_vector_type(8))) _Float16 f16x8;
typedef __attribute__((ext_vector_type(4))) _Float16 f16x4;
typedef __attribute__((ext_vector_type(4))) float f32x4;

#define L2E 1.44269504088896f

// Exact-erf GELU via Abramowitz-Stegun 7.1.26 (|erf err| < 1.5e-7), branch-free.
__device__ __forceinline__ float gelu_exact(float v) {
  float x  = v * 0.70710678118f;
  float ax = __builtin_fabsf(x);
  float t  = __builtin_amdgcn_rcpf(__builtin_fmaf(0.3275911f, ax, 1.0f));
  float poly = t * __builtin_fmaf(t,
                 __builtin_fmaf(t,
                   __builtin_fmaf(t,
                     __builtin_fmaf(t, 1.061405429f, -1.453152027f),
                   1.421413741f),
                 -0.284496736f),
               0.254829592f);
  float e    = __builtin_amdgcn_exp2f(-L2E * x * x);
  float erfa = __builtin_fmaf(-poly, e, 1.0f);
  float erfx = copysignf(erfa, x);
  return 0.5f * v * (1.0f + erfx);
}

// async global->LDS, 16B per lane. LDS dest = wave-uniform base + lane*16 (HW).
__device__ __forceinline__ void gl2lds16(const void* g, void* l) {
  __builtin_amdgcn_global_load_lds(
      (const __attribute__((address_space(1))) void*)g,
      (__attribute__((address_space(3))) void*)l, 16, 0, 0);
}

// ---------------------------------------------------------------------------
// Kernel 1: q/k projections (f16 MFMA, f32 accum, +bias) and x -> V^T (f16).
// ---------------------------------------------------------------------------
__global__ __launch_bounds__(256) void proj_tr_kernel(
    const float* __restrict__ x,
    const float* __restrict__ W1, const float* __restrict__ b1,
    const float* __restrict__ W2, const float* __restrict__ b2,
    _Float16* __restrict__ Qb, _Float16* __restrict__ Kb,
    _Float16* __restrict__ VT)
{
  const int tid  = threadIdx.x;
  const int wave = tid >> 6;
  const int lane = tid & 63;
  const int lhi  = lane >> 4;
  const int llo  = lane & 15;
  const int r0   = blockIdx.x * 64;
  const int wr0  = r0 + wave * 16;

  f16x8 a[4];
#pragma unroll
  for (int ks = 0; ks < 4; ++ks) {
    const float* p = x + (size_t)(wr0 + llo) * D_ + lhi * 8 + ks * 32;
    f16x8 t;
#pragma unroll
    for (int e = 0; e < 8; ++e) t[e] = (_Float16)p[e];
    a[ks] = t;
  }

  f32x4 accq[8], acck[8];
#pragma unroll
  for (int n = 0; n < 8; ++n) {
    accq[n] = (f32x4){0.f, 0.f, 0.f, 0.f};
    acck[n] = (f32x4){0.f, 0.f, 0.f, 0.f};
  }

#pragma unroll
  for (int n = 0; n < 8; ++n) {
    const int e = n * 16 + llo;
#pragma unroll
    for (int ks = 0; ks < 4; ++ks) {
      const float* p1 = W1 + e * D_ + lhi * 8 + ks * 32;
      const float* p2 = W2 + e * D_ + lhi * 8 + ks * 32;
      f16x8 w1f, w2f;
#pragma unroll
      for (int q = 0; q < 8; ++q) {
        w1f[q] = (_Float16)p1[q];
        w2f[q] = (_Float16)p2[q];
      }
      accq[n] = __builtin_amdgcn_mfma_f32_16x16x32_f16(a[ks], w1f, accq[n], 0, 0, 0);
      acck[n] = __builtin_amdgcn_mfma_f32_16x16x32_f16(a[ks], w2f, acck[n], 0, 0, 0);
    }
  }

#pragma unroll
  for (int n = 0; n < 8; ++n) {
    const int e = n * 16 + llo;
    const float bias1 = b1[e];
    const float bias2 = b2[e];
#pragma unroll
    for (int r = 0; r < 4; ++r) {
      const size_t row = (size_t)wr0 + lhi * 4 + r;
      Qb[row * D_ + e] = (_Float16)(accq[n][r] + bias1);
      Kb[row * D_ + e] = (_Float16)(acck[n][r] + bias2);
    }
  }

  const int bh = r0 / L_;
  const int l0 = r0 % L_;
  const int d  = tid & 127;
  const int rh = tid >> 7;
  _Float16* dst = VT + (size_t)bh * D_ * L_ + (size_t)d * L_ + l0 + rh * 32;
#pragma unroll
  for (int j = 0; j < 4; ++j) {
    f16x8 t;
#pragma unroll
    for (int e = 0; e < 8; ++e)
      t[e] = (_Float16)x[(size_t)(r0 + rh * 32 + j * 8 + e) * D_ + d];
    *(f16x8*)(dst + j * 8) = t;
  }
}

// ---------------------------------------------------------------------------
// Kernel 2: fused gelu(QK^T)->softmax->@V flash attention.
// 8 waves/block, 128 q-rows/block (16/wave). K/V tiles (64 k) staged in LDS
// via global_load_lds (linear dest + inverse-swizzled source; XOR-swizzled
// reads), double-buffered, prefetch-before-compute, 1 barrier/tile.
// Swapped QK^T -> in-lane softmax; defer-max (THR=8) skips accO rescale.
// ---------------------------------------------------------------------------
__global__ __launch_bounds__(512, 4) void attn_kernel(
    const _Float16* __restrict__ Qb, const _Float16* __restrict__ Kb,
    const _Float16* __restrict__ VT, float* __restrict__ out)
{
  __shared__ _Float16 Ks[2][64 * 128];   // 2 x 16KB, swizzled: byte^((row&7)<<4)
  __shared__ _Float16 Vs[2][128 * 64];   // 2 x 16KB, swizzled: byte^((d&7)<<4)
  __shared__ _Float16 Pl[8][1024];       // per-wave 16x64 P tile

  const int tid  = threadIdx.x;
  const int wave = tid >> 6;      // 0..7
  const int lane = tid & 63;
  const int lhi  = lane >> 4;
  const int llo  = lane & 15;

  // XCD-aware swizzle: 1024 blocks, 8 XCDs -> each XCD gets 8 whole heads.
  const int bid = blockIdx.x;
  const int blk = (bid & 7) * 128 + (bid >> 3);
  const int bh  = blk >> 4;           // 16 q-blocks (128 rows) per head
  const int q0  = (blk & 15) * 128;
  const int b   = bh >> 4;
  const int h   = bh & 15;
  const int wq0 = q0 + wave * 16;

  const char* Khead = (const char*)(Kb + (size_t)bh * L_ * D_);
  const char* Vhead = (const char*)(VT + (size_t)bh * D_ * L_);

  // ---- staging constants ----
  // K: 16KB tile = 8 waves x 2 calls x 1KB. LDS linear; source pre-swizzled.
  const int l4 = lane >> 4, l16 = lane & 15;
  int klds[2], ksrc[2], vlds[2], vsrc[2];
#pragma unroll
  for (int c = 0; c < 2; ++c) {
    klds[c] = wave * 2048 + c * 1024;                     // wave-uniform dest
    ksrc[c] = wave * 2048 + c * 1024 + l4 * 256 +
              ((l16 * 16) ^ ((c * 4 + l4) << 4));          // per-lane source
    vlds[c] = (wave * 2 + c) * 1024;
    int d   = (wave * 2 + c) * 8 + (lane >> 3);
    vsrc[c] = d * 4096 + (((lane & 7) * 16) ^ ((lane >> 3) << 4));
  }

  // Q fragments (B-operand of swapped QK^T): col j = llo = q-row
  f16x8 qf[4];
#pragma unroll
  for (int ks = 0; ks < 4; ++ks)
    qf[ks] = *(const f16x8*)(Qb + ((size_t)bh * L_ + wq0 + llo) * D_ + lhi * 8 + ks * 32);

  f32x4 accO[8];
#pragma unroll
  for (int n = 0; n < 8; ++n) accO[n] = (f32x4){0.f, 0.f, 0.f, 0.f};
  float m = -1e30f;
  float l = 0.f;

  _Float16* pw = Pl[wave];
  const int pswz = (llo & 7) << 3;           // P-buffer swizzle (half units)
  const int cswz = (llo & 7) << 3;           // K/V read swizzle (half units)
  const int pwb  = llo * 64 + lhi * 4;

  // ---- prologue: stage tile 0 ----
#pragma unroll
  for (int c = 0; c < 2; ++c) {
    gl2lds16(Khead + ksrc[c], (char*)&Ks[0][0] + klds[c]);
    gl2lds16(Vhead + vsrc[c], (char*)&Vs[0][0] + vlds[c]);
  }
  __syncthreads();

  int cur = 0;
  for (int j0 = 0; j0 < L_; j0 += 64) {
    // ---- prefetch next tile into buf cur^1 (loads stay in flight) ----
    if (j0 + 64 < L_) {
      const char* kt = Khead + (size_t)(j0 + 64) * 256;
      const char* vt = Vhead + (size_t)(j0 + 64) * 2;
#pragma unroll
      for (int c = 0; c < 2; ++c) {
        gl2lds16(kt + ksrc[c], (char*)&Ks[cur ^ 1][0] + klds[c]);
        gl2lds16(vt + vsrc[c], (char*)&Vs[cur ^ 1][0] + vlds[c]);
      }
    }

    // ---- S^T = K Q^T : lane holds S[q=llo][k=j0+js*16+lhi*4+r] ----
    const _Float16* kbuf = &Ks[cur][0];
    f32x4 s[4];
#pragma unroll
    for (int js = 0; js < 4; ++js) s[js] = (f32x4){0.f, 0.f, 0.f, 0.f};
#pragma unroll
    for (int js = 0; js < 4; ++js) {
      const int rb = (js * 16 + llo) * 128;
#pragma unroll
      for (int ks = 0; ks < 4; ++ks) {
        f16x8 kf = *(const f16x8*)(kbuf + rb + ((lhi * 8 + ks * 32) ^ cswz));
        s[js] = __builtin_amdgcn_mfma_f32_16x16x32_f16(kf, qf[ks], s[js], 0, 0, 0);
      }
    }

    // ---- GELU (exact erf, branch-free) ----
#pragma unroll
    for (int js = 0; js < 4; ++js)
#pragma unroll
      for (int r = 0; r < 4; ++r) s[js][r] = gelu_exact(s[js][r]);

    // ---- online softmax with defer-max (THR=8) ----
    float tm = fmaxf(fmaxf(fmaxf(s[0][0], s[0][1]), fmaxf(s[0][2], s[0][3])),
                     fmaxf(fmaxf(s[1][0], s[1][1]), fmaxf(s[1][2], s[1][3])));
    float tm2 = fmaxf(fmaxf(fmaxf(s[2][0], s[2][1]), fmaxf(s[2][2], s[2][3])),
                      fmaxf(fmaxf(s[3][0], s[3][1]), fmaxf(s[3][2], s[3][3])));
    tm = fmaxf(tm, tm2);
    tm = fmaxf(tm, __shfl_xor(tm, 16));
    tm = fmaxf(tm, __shfl_xor(tm, 32));

    f16x4 pj[4];
    float ts = 0.f;
    if (__all(tm <= m + 8.f)) {
      // no rescale: keep m, P bounded by e^8 (f16-safe)
      const float mnl = m * L2E;
#pragma unroll
      for (int js = 0; js < 4; ++js)
#pragma unroll
        for (int r = 0; r < 4; ++r) {
          float p = __builtin_amdgcn_exp2f(__builtin_fmaf(s[js][r], L2E, -mnl));
          ts += p;
          pj[js][r] = (_Float16)p;
        }
      ts += __shfl_xor(ts, 16);
      ts += __shfl_xor(ts, 32);
      l += ts;
    } else {
      float mn  = fmaxf(m, tm);
      const float mnl = mn * L2E;
      float sc  = __builtin_amdgcn_exp2f(__builtin_fmaf(m, L2E, -mnl));
      m = mn;
#pragma unroll
      for (int js = 0; js < 4; ++js)
#pragma unroll
        for (int r = 0; r < 4; ++r) {
          float p = __builtin_amdgcn_exp2f(__builtin_fmaf(s[js][r], L2E, -mnl));
          ts += p;
          pj[js][r] = (_Float16)p;
        }
      ts += __shfl_xor(ts, 16);
      ts += __shfl_xor(ts, 32);
      l = __builtin_fmaf(l, sc, ts);
      float scb[4];
#pragma unroll
      for (int r = 0; r < 4; ++r) scb[r] = __shfl(sc, lhi * 4 + r);
#pragma unroll
      for (int n = 0; n < 8; ++n)
#pragma unroll
        for (int r = 0; r < 4; ++r) accO[n][r] *= scb[r];
    }

    // ---- P -> wave-private LDS ----
#pragma unroll
    for (int js = 0; js < 4; ++js)
      *(f16x4*)(pw + ((pwb + js * 16) ^ pswz)) = pj[js];

    // ---- O += P @ V (V from LDS) ----
    const _Float16* vbuf = &Vs[cur][0];
#pragma unroll
    for (int ks2 = 0; ks2 < 2; ++ks2) {
      const int koff = lhi * 8 + ks2 * 32;
      f16x8 pf = *(const f16x8*)(pw + ((llo * 64 + koff) ^ pswz));
#pragma unroll
      for (int n = 0; n < 8; ++n) {
        f16x8 vf = *(const f16x8*)(vbuf + (n * 16 + llo) * 64 + (koff ^ cswz));
        accO[n] = __builtin_amdgcn_mfma_f32_16x16x32_f16(pf, vf, accO[n], 0, 0, 0);
      }
    }

    __syncthreads();   // drains vmcnt (staging done) + all waves done with cur
    cur ^= 1;
  }

  // ---- epilogue ----
  float linv = __builtin_amdgcn_rcpf(l);
  float lb[4];
#pragma unroll
  for (int r = 0; r < 4; ++r) lb[r] = __shfl(linv, lhi * 4 + r);
#pragma unroll
  for (int n = 0; n < 8; ++n) {
    const int dcol = n * 16 + llo;
#pragma unroll
    for (int r = 0; r < 4; ++r) {
      const int i = wq0 + lhi * 4 + r;
      out[((size_t)(b * L_ + i) * H_ + h) * D_ + dcol] = accO[n][r] * lb[r];
    }
  }
}

extern "C" void kernel_launch(void* const* d_in, const int* in_sizes, int n_in,
                              void* d_out, int out_size, void* d_ws, size_t ws_size,
                              hipStream_t stream) {
  const float* x  = (const float*)d_in[0];
  const float* W1 = (const float*)d_in[1];
  const float* b1 = (const float*)d_in[2];
  const float* W2 = (const float*)d_in[3];
  const float* b2 = (const float*)d_in[4];
  float* out = (float*)d_out;

  const size_t N = (size_t)BH_ * L_ * D_;
  _Float16* Qb = (_Float16*)d_ws;
  _Float16* Kb = Qb + N;
  _Float16* VT = Kb + N;

  proj_tr_kernel<<<(BH_ * L_) / 64, 256, 0, stream>>>(x, W1, b1, W2, b2, Qb, Kb, VT);
  attn_kernel<<<BH_ * (L_ / 128), 512, 0, stream>>>(Qb, Kb, VT, out);
}